// Round 2
// baseline (7745.865 us; speedup 1.0000x reference)
//
#include <hip/hip_runtime.h>
#include <hip/hip_bf16.h>
#include <stdint.h>
#include <stddef.h>

// NeuralODE: y' = MLP(y), Dormand-Prince 6-stage RK, 10 intervals x 4 substeps.
// Persistent kernel: 64 WGs x 16 batch rows. Weights bf16 in d_ws, streamed
// from XCD-local L2 every eval. D = W(A) . act^T(B) with mfma_f32_16x16x32_bf16.
// RK state in registers. Round 2: no VGPR cap (was spilling), depth-4 register
// pipeline for weight loads, lgkm-only barriers, bias folded into acc init.

typedef __bf16 bf16x8 __attribute__((ext_vector_type(8)));
typedef __bf16 bf16x4 __attribute__((ext_vector_type(4)));
typedef float  f32x4  __attribute__((ext_vector_type(4)));

#define DD 256
#define HH 512
#define MROWS 16
#define RA 264   // 256 + 8 pad: 33 16B-chunks/row -> 2-way-max LDS aliasing (free)
#define RH 520   // 512 + 8 pad: 65 chunks/row

// ---- weight fp32 -> bf16 conversion (runs every launch; ws re-poisoned) ----
__global__ void cvt_w(const float* __restrict__ W1, const float* __restrict__ W2,
                      const float* __restrict__ W3, __bf16* __restrict__ o)
{
    int i = blockIdx.x * blockDim.x + threadIdx.x;  // 0 .. 524287
    float v;
    if (i < HH * DD)                 v = W1[i];
    else if (i < HH * DD + HH * HH)  v = W2[i - HH * DD];
    else                             v = W3[i - (HH * DD + HH * HH)];
    o[i] = (__bf16)v;
}

// Barrier that does NOT drain vmcnt: cross-wave communication is LDS-only,
// so lgkmcnt(0) + s_barrier suffices; prefetched global loads stay in flight.
__device__ __forceinline__ void wg_barrier() {
    asm volatile("s_waitcnt lgkmcnt(0)" ::: "memory");
    __builtin_amdgcn_s_barrier();
    asm volatile("" ::: "memory");
}

// One layer: acc[i] (i<NT tiles of 16 output-neurons) = W[rows] x act^T + bias.
// A-prologue (global) and bias load are issued BEFORE the barrier protecting
// `act`, so L2 latency overlaps barrier arrival skew. Depth-4 kb pipeline.
template<int K, int NT>
__device__ __forceinline__ void layer(const __bf16* __restrict__ W, int nbase,
                                      const float* __restrict__ bias, int bbase,
                                      const __bf16* __restrict__ act, int rs,
                                      int lr, int lg, f32x4* acc)
{
    constexpr int NKB = K / 32;
    const __bf16* wp = W + (size_t)(nbase + lr) * K + lg * 8;
    const __bf16* ap = act + lr * rs + lg * 8;

    bf16x8 a0[NT], a1[NT], a2[NT], a3[NT];
    bf16x8 b0, b1, b2, b3;

    // A-frag prologue: kb = 0..3 (independent of LDS; issue before barrier)
#pragma unroll
    for (int i = 0; i < NT; ++i) a0[i] = *(const bf16x8*)(wp + 0 * 32 + (size_t)i * (16 * K));
#pragma unroll
    for (int i = 0; i < NT; ++i) a1[i] = *(const bf16x8*)(wp + 1 * 32 + (size_t)i * (16 * K));
#pragma unroll
    for (int i = 0; i < NT; ++i) a2[i] = *(const bf16x8*)(wp + 2 * 32 + (size_t)i * (16 * K));
#pragma unroll
    for (int i = 0; i < NT; ++i) a3[i] = *(const bf16x8*)(wp + 3 * 32 + (size_t)i * (16 * K));

    // bias -> accumulator init (same value for all 16 batch cols of a lane-row)
#pragma unroll
    for (int i = 0; i < NT; ++i)
        acc[i] = *(const f32x4*)(bias + bbase + i * 16 + lg * 4);

    wg_barrier();   // act (LDS) now consistent across waves

    b0 = *(const bf16x8*)(ap + 0 * 32);
    b1 = *(const bf16x8*)(ap + 1 * 32);
    b2 = *(const bf16x8*)(ap + 2 * 32);
    b3 = *(const bf16x8*)(ap + 3 * 32);

#define STAGE(AB, BB, KBOFF)                                                     \
    {                                                                            \
        bf16x8 tb = BB;                                                          \
        bf16x8 ta[NT];                                                           \
        _Pragma("unroll")                                                        \
        for (int i = 0; i < NT; ++i) ta[i] = AB[i];                              \
        if (kb + (KBOFF) + 4 < NKB) {                                            \
            BB = *(const bf16x8*)(ap + (kb + (KBOFF) + 4) * 32);                 \
            _Pragma("unroll")                                                    \
            for (int i = 0; i < NT; ++i)                                         \
                AB[i] = *(const bf16x8*)(wp + (kb + (KBOFF) + 4) * 32            \
                                         + (size_t)i * (16 * K));               \
        }                                                                        \
        _Pragma("unroll")                                                        \
        for (int i = 0; i < NT; ++i)                                             \
            acc[i] = __builtin_amdgcn_mfma_f32_16x16x32_bf16(ta[i], tb, acc[i], 0, 0, 0); \
    }

#pragma unroll
    for (int kb = 0; kb < NKB; kb += 4) {
        STAGE(a0, b0, 0)
        STAGE(a1, b1, 1)
        STAGE(a2, b2, 2)
        STAGE(a3, b3, 3)
    }
#undef STAGE
}

__global__ __launch_bounds__(512, 1)
void ode_kernel(const float* __restrict__ x0, const int* __restrict__ Tp,
                const __bf16* __restrict__ W1, const __bf16* __restrict__ W2,
                const __bf16* __restrict__ W3,
                const float* __restrict__ b1, const float* __restrict__ b2,
                const float* __restrict__ b3, float* __restrict__ out)
{
    __shared__ __bf16 sA [MROWS * RA];   // y_stage  [16][264] bf16
    __shared__ __bf16 sH1[MROWS * RH];   // h1       [16][520] bf16
    __shared__ __bf16 sH2[MROWS * RH];   // h2       [16][520] bf16

    const int   nT = *Tp - 1;
    const float hs = 10.0f / (float)nT * 0.25f;   // T_TOTAL/(T-1)/SUBSTEPS

    const int tid  = threadIdx.x;
    const int wave = tid >> 6;
    const int lane = tid & 63;
    const int lr   = lane & 15;   // A-row / B-col / D-col index
    const int lg   = lane >> 4;   // k-group (0..3); D-rows = lg*4+j
    const int row  = blockIdx.x * MROWS + lr;

    // ---- RK state in registers: wave owns d-tiles {wave*2, wave*2+1} ----
    f32x4 yy[2];
#pragma unroll
    for (int i = 0; i < 2; ++i)
        yy[i] = *(const f32x4*)(x0 + (size_t)row * DD + wave * 32 + i * 16 + lg * 4);

    f32x4 k1v[2], k2v[2], k3v[2], k4v[2], k5v[2], k6v[2];

    __bf16* sAw  = sA  + lr * RA + wave * 32 + lg * 4;
    __bf16* sH1w = sH1 + lr * RH + wave * 64 + lg * 4;
    __bf16* sH2w = sH2 + lr * RH + wave * 64 + lg * 4;

    auto store_stage = [&](f32x4 a, f32x4 b) {
        bf16x4 v0, v1;
#pragma unroll
        for (int j = 0; j < 4; ++j) { v0[j] = (__bf16)a[j]; v1[j] = (__bf16)b[j]; }
        *(bf16x4*)(sAw)      = v0;
        *(bf16x4*)(sAw + 16) = v1;
    };

    auto mlp = [&](f32x4* kout) {
        f32x4 acc[4];
        layer<DD, 4>(W1, wave * 64, b1, wave * 64, sA, RA, lr, lg, acc);
#pragma unroll
        for (int i = 0; i < 4; ++i) {
            bf16x4 v;
#pragma unroll
            for (int j = 0; j < 4; ++j) v[j] = (__bf16)fmaxf(acc[i][j], 0.0f);
            *(bf16x4*)(sH1w + i * 16) = v;
        }
        layer<HH, 4>(W2, wave * 64, b2, wave * 64, sH1, RH, lr, lg, acc);
#pragma unroll
        for (int i = 0; i < 4; ++i) {
            bf16x4 v;
#pragma unroll
            for (int j = 0; j < 4; ++j) v[j] = (__bf16)fmaxf(acc[i][j], 0.0f);
            *(bf16x4*)(sH2w + i * 16) = v;
        }
        f32x4 acc3[2];
        layer<HH, 2>(W3, wave * 32, b3, wave * 32, sH2, RH, lr, lg, acc3);
#pragma unroll
        for (int i = 0; i < 2; ++i) kout[i] = acc3[i];
    };

    for (int t = 0; t < nT; ++t) {
        for (int ss = 0; ss < 4; ++ss) {
            store_stage(yy[0], yy[1]);
            mlp(k1v);

            store_stage(yy[0] + hs * (0.2f * k1v[0]),
                        yy[1] + hs * (0.2f * k1v[1]));
            mlp(k2v);

            store_stage(yy[0] + hs * ((3.0f/40.0f)*k1v[0] + (9.0f/40.0f)*k2v[0]),
                        yy[1] + hs * ((3.0f/40.0f)*k1v[1] + (9.0f/40.0f)*k2v[1]));
            mlp(k3v);

            store_stage(yy[0] + hs * ((float)(44.0/45.0)*k1v[0] - (float)(56.0/15.0)*k2v[0]
                                     + (float)(32.0/9.0)*k3v[0]),
                        yy[1] + hs * ((float)(44.0/45.0)*k1v[1] - (float)(56.0/15.0)*k2v[1]
                                     + (float)(32.0/9.0)*k3v[1]));
            mlp(k4v);

            store_stage(yy[0] + hs * ((float)(19372.0/6561.0)*k1v[0] - (float)(25360.0/2187.0)*k2v[0]
                                     + (float)(64448.0/6561.0)*k3v[0] - (float)(212.0/729.0)*k4v[0]),
                        yy[1] + hs * ((float)(19372.0/6561.0)*k1v[1] - (float)(25360.0/2187.0)*k2v[1]
                                     + (float)(64448.0/6561.0)*k3v[1] - (float)(212.0/729.0)*k4v[1]));
            mlp(k5v);

            store_stage(yy[0] + hs * ((float)(9017.0/3168.0)*k1v[0] - (float)(355.0/33.0)*k2v[0]
                                     + (float)(46732.0/5247.0)*k3v[0] + (float)(49.0/176.0)*k4v[0]
                                     - (float)(5103.0/18656.0)*k5v[0]),
                        yy[1] + hs * ((float)(9017.0/3168.0)*k1v[1] - (float)(355.0/33.0)*k2v[1]
                                     + (float)(46732.0/5247.0)*k3v[1] + (float)(49.0/176.0)*k4v[1]
                                     - (float)(5103.0/18656.0)*k5v[1]));
            mlp(k6v);

#pragma unroll
            for (int i = 0; i < 2; ++i)
                yy[i] = yy[i] + hs * ((float)(35.0/384.0)*k1v[i] + (float)(500.0/1113.0)*k3v[i]
                                     + (float)(125.0/192.0)*k4v[i] + (float)(-2187.0/6784.0)*k5v[i]
                                     + (float)(11.0/84.0)*k6v[i]);
        }
        // emit y at interval end: out[b][t][d]
#pragma unroll
        for (int i = 0; i < 2; ++i)
            *(f32x4*)(out + ((size_t)row * nT + t) * DD + wave * 32 + i * 16 + lg * 4) = yy[i];
    }
}

extern "C" void kernel_launch(void* const* d_in, const int* in_sizes, int n_in,
                              void* d_out, int out_size, void* d_ws, size_t ws_size,
                              hipStream_t stream)
{
    const float* x0 = (const float*)d_in[0];
    const int*   Tp = (const int*)  d_in[1];
    const float* W1 = (const float*)d_in[2];
    const float* b1 = (const float*)d_in[3];
    const float* W2 = (const float*)d_in[4];
    const float* b2 = (const float*)d_in[5];
    const float* W3 = (const float*)d_in[6];
    const float* b3 = (const float*)d_in[7];

    const int B = in_sizes[0] / DD;          // 1024

    __bf16* wb = (__bf16*)d_ws;              // 1 MiB: W1b | W2b | W3b
    const int nconv = HH * DD + HH * HH + DD * HH;   // 524288
    cvt_w<<<nconv / 256, 256, 0, stream>>>(W1, W2, W3, wb);

    ode_kernel<<<B / MROWS, 512, 0, stream>>>(x0, Tp,
                                              wb, wb + HH * DD, wb + HH * DD + HH * HH,
                                              b1, b2, b3, (float*)d_out);
}

// Round 3
// 6505.769 us; speedup vs baseline: 1.1906x; 1.1906x over previous
//
#include <hip/hip_runtime.h>
#include <hip/hip_bf16.h>
#include <stdint.h>
#include <stddef.h>

// NeuralODE: y' = MLP(y), Dormand-Prince 6-stage RK, 10 intervals x 4 substeps.
// Round 3: WEIGHTS IN REGISTERS. 64 WGs x 16 batch rows, 16 waves/WG
// (4 waves/SIMD, 512-VGPR budget). Each wave permanently holds its neuron
// slice of W1/W2/W3 as 256 pinned VGPRs (loaded once); the 240 sequential
// MLP evals then touch global memory ZERO times in the K-loops.
// Activations (16 rows) stay in LDS; all matmuls D = W(A) . act^T(B) with
// mfma_f32_16x16x32_bf16 (layout validated in rounds 1-2). lgkm-only barriers.

typedef __bf16 bf16x8 __attribute__((ext_vector_type(8)));
typedef __bf16 bf16x4 __attribute__((ext_vector_type(4)));
typedef float  f32x4  __attribute__((ext_vector_type(4)));
typedef int    i32x4  __attribute__((ext_vector_type(4)));

#define DD 256
#define HH 512
#define RA 264   // 256 + 8 pad: row stride 528B -> 2-way max LDS aliasing (free)
#define RH 520   // 512 + 8 pad: row stride 1040B -> 2-way max

// ---- weight fp32 -> bf16 conversion (runs every launch; ws re-poisoned) ----
__global__ void cvt_w(const float* __restrict__ W1, const float* __restrict__ W2,
                      const float* __restrict__ W3, __bf16* __restrict__ o)
{
    int i = blockIdx.x * blockDim.x + threadIdx.x;  // 0 .. 524287
    float v;
    if (i < HH * DD)                 v = W1[i];
    else if (i < HH * DD + HH * HH)  v = W2[i - HH * DD];
    else                             v = W3[i - (HH * DD + HH * HH)];
    o[i] = (__bf16)v;
}

// Barrier that does NOT drain vmcnt (cross-wave traffic is LDS-only; the
// main loop has no global loads at all, and out-stores need no ordering).
__device__ __forceinline__ void wg_barrier() {
    asm volatile("s_waitcnt lgkmcnt(0)" ::: "memory");
    __builtin_amdgcn_s_barrier();
    asm volatile("" ::: "memory");
}

// acc[i] = bias[i] + W(frags, registers) . act^T(LDS).
// ap = act + lr*row_stride + lg*8; one ds_read_b128 per kb feeds NT MFMAs.
template<int KB, int NT>
__device__ __forceinline__ void run_layer(const i32x4 (&wf)[NT][KB],
                                          const f32x4 (&bv)[NT],
                                          const __bf16* ap, f32x4 (&acc)[NT])
{
#pragma unroll
    for (int i = 0; i < NT; ++i) acc[i] = bv[i];
#pragma unroll
    for (int kb = 0; kb < KB; ++kb) {
        bf16x8 b = *(const bf16x8*)(ap + kb * 32);
#pragma unroll
        for (int i = 0; i < NT; ++i)
            acc[i] = __builtin_amdgcn_mfma_f32_16x16x32_bf16(
                __builtin_bit_cast(bf16x8, wf[i][kb]), b, acc[i], 0, 0, 0);
    }
}

__global__ __launch_bounds__(1024) __attribute__((amdgpu_waves_per_eu(4, 4)))
void ode_kernel(const float* __restrict__ x0, const int* __restrict__ Tp,
                const __bf16* __restrict__ W1, const __bf16* __restrict__ W2,
                const __bf16* __restrict__ W3,
                const float* __restrict__ b1, const float* __restrict__ b2,
                const float* __restrict__ b3, float* __restrict__ out)
{
    __shared__ __bf16 sA [16 * RA];   // y_stage  [batch16][264]
    __shared__ __bf16 sH1[16 * RH];   // h1       [batch16][520]
    __shared__ __bf16 sH2[16 * RH];   // h2       [batch16][520]

    const int   nT = *Tp - 1;
    const float hs = 10.0f / (float)nT * 0.25f;   // T_TOTAL/(T-1)/SUBSTEPS

    const int tid  = threadIdx.x;
    const int w    = tid >> 6;    // wave 0..15: owns neurons [w*32,w*32+32) (l1,l2), dims [w*16,w*16+16) (l3)
    const int lane = tid & 63;
    const int lr   = lane & 15;   // weight-row (A) / batch-row (B,D col)
    const int lg   = lane >> 4;   // k-group; D rows = lg*4+j
    const int brow = blockIdx.x * 16 + lr;

    // ---- load weight fragments into registers, once ----
    i32x4 wf1[2][8], wf2[2][16], wf3[1][16];
    {
        const __bf16* p1 = W1 + (size_t)(w * 32 + lr) * DD + lg * 8;
#pragma unroll
        for (int i = 0; i < 2; ++i)
#pragma unroll
            for (int kb = 0; kb < 8; ++kb)
                wf1[i][kb] = *(const i32x4*)(p1 + i * 16 * DD + kb * 32);
        const __bf16* p2 = W2 + (size_t)(w * 32 + lr) * HH + lg * 8;
#pragma unroll
        for (int i = 0; i < 2; ++i)
#pragma unroll
            for (int kb = 0; kb < 16; ++kb)
                wf2[i][kb] = *(const i32x4*)(p2 + i * 16 * HH + kb * 32);
        const __bf16* p3 = W3 + (size_t)(w * 16 + lr) * HH + lg * 8;
#pragma unroll
        for (int kb = 0; kb < 16; ++kb)
            wf3[0][kb] = *(const i32x4*)(p3 + kb * 32);
    }
    // Pin: opaque to the compiler -> cannot rematerialize the loads in-loop.
#pragma unroll
    for (int i = 0; i < 2; ++i)
#pragma unroll
        for (int kb = 0; kb < 8; ++kb)  asm volatile("" : "+v"(wf1[i][kb]));
#pragma unroll
    for (int i = 0; i < 2; ++i)
#pragma unroll
        for (int kb = 0; kb < 16; ++kb) asm volatile("" : "+v"(wf2[i][kb]));
#pragma unroll
    for (int kb = 0; kb < 16; ++kb)     asm volatile("" : "+v"(wf3[0][kb]));

    // ---- biases in registers ----
    f32x4 bv1[2], bv2[2], bv3[1];
#pragma unroll
    for (int i = 0; i < 2; ++i) {
        bv1[i] = *(const f32x4*)(b1 + w * 32 + i * 16 + lg * 4);
        bv2[i] = *(const f32x4*)(b2 + w * 32 + i * 16 + lg * 4);
    }
    bv3[0] = *(const f32x4*)(b3 + w * 16 + lg * 4);

    // ---- RK state: this lane holds dims [w*16+lg*4 .. +4) of batch row lr ----
    f32x4 yy = *(const f32x4*)(x0 + (size_t)brow * DD + w * 16 + lg * 4);
    f32x4 k1, k2, k3, k4, k5, k6;

    __bf16*       sAw  = sA  + lr * RA + w * 16 + lg * 4;
    __bf16*       sH1w = sH1 + lr * RH + w * 32 + lg * 4;
    __bf16*       sH2w = sH2 + lr * RH + w * 32 + lg * 4;
    const __bf16* apA  = sA  + lr * RA + lg * 8;
    const __bf16* apH1 = sH1 + lr * RH + lg * 8;
    const __bf16* apH2 = sH2 + lr * RH + lg * 8;

    auto store_stage = [&](f32x4 v) {
        bf16x4 o;
#pragma unroll
        for (int j = 0; j < 4; ++j) o[j] = (__bf16)v[j];
        *(bf16x4*)sAw = o;
    };

    auto mlp = [&](f32x4& kout) {
        wg_barrier();                           // sA written by all waves
        f32x4 acc[2];
        run_layer<8, 2>(wf1, bv1, apA, acc);
#pragma unroll
        for (int i = 0; i < 2; ++i) {
            bf16x4 v;
#pragma unroll
            for (int j = 0; j < 4; ++j) v[j] = (__bf16)fmaxf(acc[i][j], 0.0f);
            *(bf16x4*)(sH1w + i * 16) = v;
        }
        wg_barrier();                           // h1 ready
        run_layer<16, 2>(wf2, bv2, apH1, acc);
#pragma unroll
        for (int i = 0; i < 2; ++i) {
            bf16x4 v;
#pragma unroll
            for (int j = 0; j < 4; ++j) v[j] = (__bf16)fmaxf(acc[i][j], 0.0f);
            *(bf16x4*)(sH2w + i * 16) = v;
        }
        wg_barrier();                           // h2 ready
        f32x4 a3[1];
        run_layer<16, 1>(wf3, bv3, apH2, a3);
        kout = a3[0];
    };

    for (int t = 0; t < nT; ++t) {
        for (int ss = 0; ss < 4; ++ss) {
            store_stage(yy);
            mlp(k1);

            store_stage(yy + hs * (0.2f * k1));
            mlp(k2);

            store_stage(yy + hs * ((3.0f/40.0f)*k1 + (9.0f/40.0f)*k2));
            mlp(k3);

            store_stage(yy + hs * ((float)(44.0/45.0)*k1 - (float)(56.0/15.0)*k2
                                  + (float)(32.0/9.0)*k3));
            mlp(k4);

            store_stage(yy + hs * ((float)(19372.0/6561.0)*k1 - (float)(25360.0/2187.0)*k2
                                  + (float)(64448.0/6561.0)*k3 - (float)(212.0/729.0)*k4));
            mlp(k5);

            store_stage(yy + hs * ((float)(9017.0/3168.0)*k1 - (float)(355.0/33.0)*k2
                                  + (float)(46732.0/5247.0)*k3 + (float)(49.0/176.0)*k4
                                  - (float)(5103.0/18656.0)*k5));
            mlp(k6);

            yy = yy + hs * ((float)(35.0/384.0)*k1 + (float)(500.0/1113.0)*k3
                           + (float)(125.0/192.0)*k4 + (float)(-2187.0/6784.0)*k5
                           + (float)(11.0/84.0)*k6);
        }
        // emit y at interval end: out[b][t][d]
        *(f32x4*)(out + ((size_t)brow * nT + t) * DD + w * 16 + lg * 4) = yy;
    }
}

extern "C" void kernel_launch(void* const* d_in, const int* in_sizes, int n_in,
                              void* d_out, int out_size, void* d_ws, size_t ws_size,
                              hipStream_t stream)
{
    const float* x0 = (const float*)d_in[0];
    const int*   Tp = (const int*)  d_in[1];
    const float* W1 = (const float*)d_in[2];
    const float* b1 = (const float*)d_in[3];
    const float* W2 = (const float*)d_in[4];
    const float* b2 = (const float*)d_in[5];
    const float* W3 = (const float*)d_in[6];
    const float* b3 = (const float*)d_in[7];

    const int B = in_sizes[0] / DD;          // 1024

    __bf16* wb = (__bf16*)d_ws;              // 1 MiB: W1b | W2b | W3b
    const int nconv = HH * DD + HH * HH + DD * HH;   // 524288
    cvt_w<<<nconv / 256, 256, 0, stream>>>(W1, W2, W3, wb);

    ode_kernel<<<B / 16, 1024, 0, stream>>>(x0, Tp,
                                            wb, wb + HH * DD, wb + HH * DD + HH * HH,
                                            b1, b2, b3, (float*)d_out);
}

// Round 5
// 6100.383 us; speedup vs baseline: 1.2697x; 1.0665x over previous
//
#include <hip/hip_runtime.h>
#include <hip/hip_bf16.h>
#include <stdint.h>
#include <stddef.h>

// NeuralODE y'=MLP(y), dopri 6-stage, 10 intervals x 4 substeps = 240 seq evals.
// Round 5 (= round 4 + fence fix): 4-WG clusters (4 CUs) per 16-row batch
// group; 64 clusters = 256 CUs. Weights permanently in registers, DISTRIBUTED
// across the cluster's 32 waves (128 VGPR each; per-SIMD file is 512 VGPR ->
// 2 waves/SIMD @ 256). Activations exchanged via L2 with per-cluster
// atomic-counter sync (release add / relaxed spin / acquire fence, agent
// scope -- XCD L2s are not coherent). 3 syncs per eval, 720 total.

typedef __bf16 bf16x8 __attribute__((ext_vector_type(8)));
typedef __bf16 bf16x4 __attribute__((ext_vector_type(4)));
typedef float  f32x4  __attribute__((ext_vector_type(4)));
typedef int    i32x4  __attribute__((ext_vector_type(4)));

#define DD 256
#define HH 512
#define RA 264
#define RH 520
#define NW (HH*DD + HH*HH + DD*HH)
#define NFLAGS 2048

__global__ void cvt_w(const float* __restrict__ W1, const float* __restrict__ W2,
                      const float* __restrict__ W3, __bf16* __restrict__ o,
                      int* __restrict__ flags)
{
    int i = blockIdx.x * blockDim.x + threadIdx.x;
    if (i < NFLAGS) flags[i] = 0;
    float v;
    if (i < HH*DD)              v = W1[i];
    else if (i < HH*DD + HH*HH) v = W2[i - HH*DD];
    else                        v = W3[i - (HH*DD + HH*HH)];
    o[i] = (__bf16)v;
}

__device__ __forceinline__ void wg_barrier() {
    asm volatile("s_waitcnt lgkmcnt(0)" ::: "memory");
    __builtin_amdgcn_s_barrier();
    asm volatile("" ::: "memory");
}

__global__ __launch_bounds__(512) __attribute__((amdgpu_waves_per_eu(2, 2)))
void ode_kernel(const float* __restrict__ x0, const int* __restrict__ Tp,
                const __bf16* __restrict__ Wb,
                const float* __restrict__ b1, const float* __restrict__ b2,
                const float* __restrict__ b3,
                float* __restrict__ out,
                __bf16* __restrict__ exch, int* __restrict__ flags, int nc)
{
    __shared__ __bf16 sA[16 * RA];
    __shared__ __bf16 sH[16 * RH];
    __shared__ float  sb1[HH], sb2[HH], sb3[DD];

    const int   nT = *Tp - 1;
    const float hs = 10.0f / (float)nT * 0.25f;

    const int bx   = blockIdx.x;
    const int c    = bx % nc;      // cluster id; members at bx = c + m*nc
    const int m    = bx / nc;      // member 0..3
    const int tid  = threadIdx.x;
    const int w    = tid >> 6, lane = tid & 63;
    const int lr   = lane & 15;    // A weight-row / B batch-row / D batch-col
    const int lg   = lane >> 4;    // k-group; D rows = lg*4+j
    const int gw   = m * 8 + w;    // cluster-wave 0..31

    const __bf16* W1 = Wb;
    const __bf16* W2 = Wb + HH*DD;
    const __bf16* W3 = Wb + HH*DD + HH*HH;

    __bf16* h1buf = exch + (size_t)c * 20480;   // [16][512]
    __bf16* h2buf = h1buf + 16*HH;              // [16][512]
    __bf16* sbuf  = h2buf + 16*HH;              // [16][256]
    int*    cnt   = flags + c * 32;             // own cacheline per cluster

    // ---- persistent register weights (128 VGPR/wave) ----
    // all waves: wf2 = W2 tile (neurons [gw*16,+16))
    // m<2 (gw<16):  wfx = W3 tile (dims [gw*16,+16)); also owns RK state
    // m>=2(gw>=16): wfx = two W1 tiles (neurons [(gw-16)*32,+32))
    i32x4 wf2[16], wfx[16];
    {
        const __bf16* p2 = W2 + (size_t)(gw*16 + lr)*HH + lg*8;
#pragma unroll
        for (int kb = 0; kb < 16; ++kb) wf2[kb] = *(const i32x4*)(p2 + kb*32);
    }
    if (m < 2) {
        const __bf16* p3 = W3 + (size_t)(gw*16 + lr)*HH + lg*8;
#pragma unroll
        for (int kb = 0; kb < 16; ++kb) wfx[kb] = *(const i32x4*)(p3 + kb*32);
    } else {
        const int nb = (gw - 16) * 32;
        const __bf16* p1 = W1 + (size_t)(nb + lr)*DD + lg*8;
#pragma unroll
        for (int i2 = 0; i2 < 2; ++i2)
#pragma unroll
            for (int kb = 0; kb < 8; ++kb)
                wfx[i2*8 + kb] = *(const i32x4*)(p1 + (size_t)i2*16*DD + kb*32);
    }
#pragma unroll
    for (int kb = 0; kb < 16; ++kb) {           // pin: no remat/sink in loop
        asm volatile("" : "+v"(wf2[kb]));
        asm volatile("" : "+v"(wfx[kb]));
    }

    if (tid < HH) { sb1[tid] = b1[tid]; sb2[tid] = b2[tid]; }
    if (tid < DD) { sb3[tid] = b3[tid]; }

    const int rb = c * 16;
    f32x4 yy = {0.f,0.f,0.f,0.f};
    f32x4 k1 = yy, k2 = yy, k3 = yy, k4 = yy, k5 = yy, k6 = yy;
    if (m < 2)
        yy = *(const f32x4*)(x0 + (size_t)(rb + lr)*DD + gw*16 + lg*4);

    {   // stage x0 -> sA (bf16), every member independently
        int r = tid >> 5, col = (tid & 31) * 8;
        f32x4 u0 = *(const f32x4*)(x0 + (size_t)(rb + r)*DD + col);
        f32x4 u1 = *(const f32x4*)(x0 + (size_t)(rb + r)*DD + col + 4);
        bf16x8 v;
#pragma unroll
        for (int j = 0; j < 4; ++j) { v[j] = (__bf16)u0[j]; v[4+j] = (__bf16)u1[j]; }
        *(bf16x8*)(sA + r*RA + col) = v;
    }
    wg_barrier();

    const __bf16* apA = sA + lr*RA + lg*8;
    const __bf16* apH = sH + lr*RH + lg*8;

    int seq = 0;
    auto csync = [&]() {   // cluster barrier: release add / relaxed spin / acquire
        ++seq;
        __syncthreads();                 // drains vmcnt(0): global stores done
        if (tid == 0) {
            __hip_atomic_fetch_add(cnt, 1, __ATOMIC_RELEASE, __HIP_MEMORY_SCOPE_AGENT);
            while (__hip_atomic_load(cnt, __ATOMIC_RELAXED, __HIP_MEMORY_SCOPE_AGENT) < 4*seq)
                __builtin_amdgcn_s_sleep(1);
            __builtin_amdgcn_fence(__ATOMIC_ACQUIRE, "agent");
        }
        __syncthreads();
    };

    auto stage16k = [&](const __bf16* src) {   // [16][512] global -> sH
        int r = tid >> 5, col = (tid & 31) * 16;
        i32x4 u0 = *(const i32x4*)(src + r*HH + col);
        i32x4 u1 = *(const i32x4*)(src + r*HH + col + 8);
        *(i32x4*)(sH + r*RH + col)     = u0;
        *(i32x4*)(sH + r*RH + col + 8) = u1;
    };

    auto mlp = [&](f32x4& kout) {   // requires sA staged + barriered
        if (m >= 2) {               // L1: waves 16..31, two 16-neuron tiles
            const int nb = (gw - 16) * 32;
            f32x4 a0 = *(const f32x4*)(sb1 + nb + lg*4);
            f32x4 a1 = *(const f32x4*)(sb1 + nb + 16 + lg*4);
#pragma unroll
            for (int kb = 0; kb < 8; ++kb) {
                bf16x8 b = *(const bf16x8*)(apA + kb*32);
                a0 = __builtin_amdgcn_mfma_f32_16x16x32_bf16(
                        __builtin_bit_cast(bf16x8, wfx[kb]),     b, a0, 0, 0, 0);
                a1 = __builtin_amdgcn_mfma_f32_16x16x32_bf16(
                        __builtin_bit_cast(bf16x8, wfx[8 + kb]), b, a1, 0, 0, 0);
            }
            bf16x4 v0, v1;
#pragma unroll
            for (int j = 0; j < 4; ++j) {
                v0[j] = (__bf16)fmaxf(a0[j], 0.0f);
                v1[j] = (__bf16)fmaxf(a1[j], 0.0f);
            }
            *(bf16x4*)(h1buf + lr*HH + nb + lg*4)      = v0;
            *(bf16x4*)(h1buf + lr*HH + nb + 16 + lg*4) = v1;
        }
        csync();                         // h1 published
        stage16k(h1buf);
        wg_barrier();
        {                                // L2: all 32 waves, one tile each
            f32x4 acc = *(const f32x4*)(sb2 + gw*16 + lg*4);
#pragma unroll
            for (int kb = 0; kb < 16; ++kb) {
                bf16x8 b = *(const bf16x8*)(apH + kb*32);
                acc = __builtin_amdgcn_mfma_f32_16x16x32_bf16(
                        __builtin_bit_cast(bf16x8, wf2[kb]), b, acc, 0, 0, 0);
            }
            bf16x4 v;
#pragma unroll
            for (int j = 0; j < 4; ++j) v[j] = (__bf16)fmaxf(acc[j], 0.0f);
            *(bf16x4*)(h2buf + lr*HH + gw*16 + lg*4) = v;
        }
        csync();                         // h2 published
        stage16k(h2buf);
        wg_barrier();
        if (m < 2) {                     // L3: waves 0..15
            f32x4 acc = *(const f32x4*)(sb3 + gw*16 + lg*4);
#pragma unroll
            for (int kb = 0; kb < 16; ++kb) {
                bf16x8 b = *(const bf16x8*)(apH + kb*32);
                acc = __builtin_amdgcn_mfma_f32_16x16x32_bf16(
                        __builtin_bit_cast(bf16x8, wfx[kb]), b, acc, 0, 0, 0);
            }
            kout = acc;
        }
    };

    auto bcast = [&](f32x4 v) {          // publish next stage vector -> all sA
        if (m < 2) {
            bf16x4 o;
#pragma unroll
            for (int j = 0; j < 4; ++j) o[j] = (__bf16)v[j];
            *(bf16x4*)(sbuf + lr*DD + gw*16 + lg*4) = o;
        }
        csync();                         // y_s published
        {
            int r = tid >> 5, col = (tid & 31) * 8;
            i32x4 u = *(const i32x4*)(sbuf + r*DD + col);
            *(i32x4*)(sA + r*RA + col) = u;
        }
        wg_barrier();
    };

    for (int t = 0; t < nT; ++t) {
        for (int ss = 0; ss < 4; ++ss) {
            mlp(k1);
            bcast(yy + hs*(0.2f*k1));
            mlp(k2);
            bcast(yy + hs*((3.0f/40.0f)*k1 + (9.0f/40.0f)*k2));
            mlp(k3);
            bcast(yy + hs*((float)(44.0/45.0)*k1 - (float)(56.0/15.0)*k2
                          + (float)(32.0/9.0)*k3));
            mlp(k4);
            bcast(yy + hs*((float)(19372.0/6561.0)*k1 - (float)(25360.0/2187.0)*k2
                          + (float)(64448.0/6561.0)*k3 - (float)(212.0/729.0)*k4));
            mlp(k5);
            bcast(yy + hs*((float)(9017.0/3168.0)*k1 - (float)(355.0/33.0)*k2
                          + (float)(46732.0/5247.0)*k3 + (float)(49.0/176.0)*k4
                          - (float)(5103.0/18656.0)*k5));
            mlp(k6);
            if (m < 2) {
                yy = yy + hs*((float)(35.0/384.0)*k1 + (float)(500.0/1113.0)*k3
                             + (float)(125.0/192.0)*k4 + (float)(-2187.0/6784.0)*k5
                             + (float)(11.0/84.0)*k6);
                if (ss == 3)
                    *(f32x4*)(out + ((size_t)(rb + lr)*nT + t)*DD + gw*16 + lg*4) = yy;
            }
            bcast(yy);   // next substep's stage-1 input
        }
    }
}

extern "C" void kernel_launch(void* const* d_in, const int* in_sizes, int n_in,
                              void* d_out, int out_size, void* d_ws, size_t ws_size,
                              hipStream_t stream)
{
    const float* x0 = (const float*)d_in[0];
    const int*   Tp = (const int*)  d_in[1];
    const float* W1 = (const float*)d_in[2];
    const float* b1 = (const float*)d_in[3];
    const float* W2 = (const float*)d_in[4];
    const float* b2 = (const float*)d_in[5];
    const float* W3 = (const float*)d_in[6];
    const float* b3 = (const float*)d_in[7];

    const int B  = in_sizes[0] / DD;     // 1024
    const int NC = B / 16;               // 64 clusters of 4 WGs

    __bf16* wb    = (__bf16*)d_ws;                                  // 1 MiB
    int*    flags = (int*)((char*)d_ws + (1 << 20));                // 8 KiB
    __bf16* exch  = (__bf16*)((char*)d_ws + (1 << 20) + 8192);      // 2.5 MiB

    cvt_w<<<NW / 256, 256, 0, stream>>>(W1, W2, W3, wb, flags);

    ode_kernel<<<NC * 4, 512, 0, stream>>>(x0, Tp, wb, b1, b2, b3,
                                           (float*)d_out, exch, flags, NC);
}

// Round 6
// 2865.786 us; speedup vs baseline: 2.7029x; 2.1287x over previous
//
#include <hip/hip_runtime.h>
#include <hip/hip_bf16.h>
#include <stdint.h>
#include <stddef.h>

// NeuralODE y'=MLP(y), dopri 6-stage RK, 10 intervals x 4 substeps = 240 seq
// MLP evals. Round 6: back to sync-free batch parallelism. 64 WGs x 16 batch
// rows, 16 waves/WG (4 waves/SIMD for TLP). Weights are NOT register-pinned:
// each wave STREAMS its neuron slice from (L2-resident) pre-swizzled weights
// every eval; with 16 waves x multiple outstanding 1KB loads the per-CU L2
// port (~154 GB/s) is the design bound: 1 MB/eval -> ~6.8 us/eval.
// cvt_w pre-swizzles weights into per-(tile,kb) lane-major order so every
// weight fetch is a single fully-coalesced dwordx4 (16B/lane = 1KB/wave).
// Cluster/sync design abandoned: agent-scope sync costs ~8.5 us (L2 wb/inv).

typedef __bf16 bf16x8 __attribute__((ext_vector_type(8)));
typedef __bf16 bf16x4 __attribute__((ext_vector_type(4)));
typedef float  f32x4  __attribute__((ext_vector_type(4)));

#define DD 256
#define HH 512
#define RA 264   // sA row stride: 528B -> lr-lanes map 2 lanes/bank (free)
#define RH 520   // sH row stride: 1040B -> same

#define W1P_OFF 0
#define W2P_OFF 131072            // 512*256
#define W3P_OFF (131072+262144)   // + 512*512

// Swizzle: Wp[(t*KB + kb)*64 + lane][8] = W[t*16 + (lane&15)][kb*32 + (lane>>4)*8 ..+8]
// One thread per 8-elem chunk: 65536 threads total.
__global__ void cvt_w(const float* __restrict__ W1, const float* __restrict__ W2,
                      const float* __restrict__ W3, __bf16* __restrict__ o)
{
    int i = blockIdx.x * blockDim.x + threadIdx.x;   // 0..65535
    const float* src;
    __bf16* dst;
    if (i < 16384) {              // W1: 32 tiles x 8 kb x 64 lanes
        int c = i, lane = c & 63, kb = (c >> 6) & 7, t = c >> 9;
        src = W1 + (size_t)(t*16 + (lane & 15))*DD + kb*32 + (lane >> 4)*8;
        dst = o + W1P_OFF + (size_t)c*8;
    } else if (i < 49152) {       // W2: 32 tiles x 16 kb x 64 lanes
        int c = i - 16384, lane = c & 63, kb = (c >> 6) & 15, t = c >> 10;
        src = W2 + (size_t)(t*16 + (lane & 15))*HH + kb*32 + (lane >> 4)*8;
        dst = o + W2P_OFF + (size_t)c*8;
    } else {                      // W3: 16 tiles x 16 kb x 64 lanes
        int c = i - 49152, lane = c & 63, kb = (c >> 6) & 15, t = c >> 10;
        src = W3 + (size_t)(t*16 + (lane & 15))*HH + kb*32 + (lane >> 4)*8;
        dst = o + W3P_OFF + (size_t)c*8;
    }
#pragma unroll
    for (int e = 0; e < 8; ++e) dst[e] = (__bf16)src[e];
}

// Barrier draining LDS only: weight loads (vmcnt) stay in flight; the
// compiler inserts its own vmcnt waits before MFMA uses.
__device__ __forceinline__ void wg_barrier() {
    asm volatile("s_waitcnt lgkmcnt(0)" ::: "memory");
    __builtin_amdgcn_s_barrier();
    asm volatile("" ::: "memory");
}

__global__ __launch_bounds__(1024) __attribute__((amdgpu_waves_per_eu(4, 4)))
void ode_kernel(const float* __restrict__ x0, const int* __restrict__ Tp,
                const __bf16* __restrict__ Wp,
                const float* __restrict__ b1, const float* __restrict__ b2,
                const float* __restrict__ b3, float* __restrict__ out)
{
    __shared__ __bf16 sA [16 * RA];   // y_stage [batch16][256] bf16
    __shared__ __bf16 sH1[16 * RH];   // h1      [batch16][512]
    __shared__ __bf16 sH2[16 * RH];   // h2      [batch16][512]
    __shared__ float  sb1[HH], sb2[HH], sb3[DD];

    const int   nT = *Tp - 1;
    const float hs = 10.0f / (float)nT * 0.25f;   // T_TOTAL/(T-1)/SUBSTEPS

    const int tid  = threadIdx.x;
    const int w    = tid >> 6;    // wave 0..15: neurons [w*32,+32) L1/L2, dims [w*16,+16) L3
    const int lane = tid & 63;
    const int lr   = lane & 15;   // weight-row within tile / batch row
    const int lg   = lane >> 4;   // k-group; D rows = lg*4+j
    const int brow = blockIdx.x * 16 + lr;

    // per-wave swizzled-weight base pointers (chunk = lane*16B within (tile,kb))
    const __bf16* wp1 = Wp + W1P_OFF + (size_t)w * 8192  + lane * 8;  // tiles 2w,2w+1 (stride 4096)
    const __bf16* wp2 = Wp + W2P_OFF + (size_t)w * 16384 + lane * 8;  // tiles 2w,2w+1 (stride 8192)
    const __bf16* wp3 = Wp + W3P_OFF + (size_t)w * 8192  + lane * 8;  // tile w

    if (tid < HH) { sb1[tid] = b1[tid]; sb2[tid] = b2[tid]; }
    if (tid < DD) { sb3[tid] = b3[tid]; }

    // RK state: lane holds dims [w*16+lg*4, +4) of batch row lr
    f32x4 yy = *(const f32x4*)(x0 + (size_t)brow * DD + w*16 + lg*4);
    f32x4 k1, k2, k3, k4, k5, k6;

    __bf16*       sAw  = sA  + lr*RA + w*16 + lg*4;
    __bf16*       sH1w = sH1 + lr*RH + w*32 + lg*4;
    __bf16*       sH2w = sH2 + lr*RH + w*32 + lg*4;
    const __bf16* apA  = sA  + lr*RA + lg*8;
    const __bf16* apH1 = sH1 + lr*RH + lg*8;
    const __bf16* apH2 = sH2 + lr*RH + lg*8;

    auto store_stage = [&](f32x4 v) {
        bf16x4 o;
#pragma unroll
        for (int j = 0; j < 4; ++j) o[j] = (__bf16)v[j];
        *(bf16x4*)sAw = o;
    };

    auto mlp = [&](f32x4& kout) {
        wg_barrier();                      // sA (and first-call sb*) ready
        // ---- L1: 2 tiles, K=256 ----
        f32x4 a0 = *(const f32x4*)(sb1 + w*32 + lg*4);
        f32x4 a1 = *(const f32x4*)(sb1 + w*32 + 16 + lg*4);
#pragma unroll
        for (int kb = 0; kb < 8; ++kb) {
            bf16x8 b   = *(const bf16x8*)(apA + kb*32);
            bf16x8 wa0 = *(const bf16x8*)(wp1 + kb*512);
            bf16x8 wa1 = *(const bf16x8*)(wp1 + 4096 + kb*512);
            a0 = __builtin_amdgcn_mfma_f32_16x16x32_bf16(wa0, b, a0, 0, 0, 0);
            a1 = __builtin_amdgcn_mfma_f32_16x16x32_bf16(wa1, b, a1, 0, 0, 0);
        }
        {
            bf16x4 v0, v1;
#pragma unroll
            for (int j = 0; j < 4; ++j) {
                v0[j] = (__bf16)fmaxf(a0[j], 0.0f);
                v1[j] = (__bf16)fmaxf(a1[j], 0.0f);
            }
            *(bf16x4*)sH1w        = v0;
            *(bf16x4*)(sH1w + 16) = v1;
        }
        wg_barrier();                      // h1 ready
        // ---- L2: 2 tiles, K=512 ----
        a0 = *(const f32x4*)(sb2 + w*32 + lg*4);
        a1 = *(const f32x4*)(sb2 + w*32 + 16 + lg*4);
#pragma unroll
        for (int kb = 0; kb < 16; ++kb) {
            bf16x8 b   = *(const bf16x8*)(apH1 + kb*32);
            bf16x8 wa0 = *(const bf16x8*)(wp2 + kb*512);
            bf16x8 wa1 = *(const bf16x8*)(wp2 + 8192 + kb*512);
            a0 = __builtin_amdgcn_mfma_f32_16x16x32_bf16(wa0, b, a0, 0, 0, 0);
            a1 = __builtin_amdgcn_mfma_f32_16x16x32_bf16(wa1, b, a1, 0, 0, 0);
        }
        {
            bf16x4 v0, v1;
#pragma unroll
            for (int j = 0; j < 4; ++j) {
                v0[j] = (__bf16)fmaxf(a0[j], 0.0f);
                v1[j] = (__bf16)fmaxf(a1[j], 0.0f);
            }
            *(bf16x4*)sH2w        = v0;
            *(bf16x4*)(sH2w + 16) = v1;
        }
        wg_barrier();                      // h2 ready
        // ---- L3: 1 tile, K=512 ----
        f32x4 a = *(const f32x4*)(sb3 + w*16 + lg*4);
#pragma unroll
        for (int kb = 0; kb < 16; ++kb) {
            bf16x8 b  = *(const bf16x8*)(apH2 + kb*32);
            bf16x8 wa = *(const bf16x8*)(wp3 + kb*512);
            a = __builtin_amdgcn_mfma_f32_16x16x32_bf16(wa, b, a, 0, 0, 0);
        }
        kout = a;
    };

    for (int t = 0; t < nT; ++t) {
        for (int ss = 0; ss < 4; ++ss) {
            store_stage(yy);
            mlp(k1);

            store_stage(yy + hs * (0.2f * k1));
            mlp(k2);

            store_stage(yy + hs * ((3.0f/40.0f)*k1 + (9.0f/40.0f)*k2));
            mlp(k3);

            store_stage(yy + hs * ((float)(44.0/45.0)*k1 - (float)(56.0/15.0)*k2
                                  + (float)(32.0/9.0)*k3));
            mlp(k4);

            store_stage(yy + hs * ((float)(19372.0/6561.0)*k1 - (float)(25360.0/2187.0)*k2
                                  + (float)(64448.0/6561.0)*k3 - (float)(212.0/729.0)*k4));
            mlp(k5);

            store_stage(yy + hs * ((float)(9017.0/3168.0)*k1 - (float)(355.0/33.0)*k2
                                  + (float)(46732.0/5247.0)*k3 + (float)(49.0/176.0)*k4
                                  - (float)(5103.0/18656.0)*k5));
            mlp(k6);

            yy = yy + hs * ((float)(35.0/384.0)*k1 + (float)(500.0/1113.0)*k3
                           + (float)(125.0/192.0)*k4 + (float)(-2187.0/6784.0)*k5
                           + (float)(11.0/84.0)*k6);
        }
        // emit y at interval end: out[b][t][d]
        *(f32x4*)(out + ((size_t)brow * nT + t) * DD + w*16 + lg*4) = yy;
    }
}

extern "C" void kernel_launch(void* const* d_in, const int* in_sizes, int n_in,
                              void* d_out, int out_size, void* d_ws, size_t ws_size,
                              hipStream_t stream)
{
    const float* x0 = (const float*)d_in[0];
    const int*   Tp = (const int*)  d_in[1];
    const float* W1 = (const float*)d_in[2];
    const float* b1 = (const float*)d_in[3];
    const float* W2 = (const float*)d_in[4];
    const float* b2 = (const float*)d_in[5];
    const float* W3 = (const float*)d_in[6];
    const float* b3 = (const float*)d_in[7];

    const int B = in_sizes[0] / DD;      // 1024

    __bf16* wb = (__bf16*)d_ws;          // 1 MiB swizzled bf16 weights
    cvt_w<<<256, 256, 0, stream>>>(W1, W2, W3, wb);

    ode_kernel<<<B / 16, 1024, 0, stream>>>(x0, Tp, wb, b1, b2, b3, (float*)d_out);
}